// Round 3
// baseline (1834.335 us; speedup 1.0000x reference)
//
#include <hip/hip_runtime.h>
#include <stdint.h>

#define SEQ 2048
#define DM 4096
#define NHEADS 16
#define DHEAD 256
#define DFF 16384

typedef __attribute__((ext_vector_type(8))) short short8;
typedef __attribute__((ext_vector_type(4))) float f32x4;
typedef __attribute__((ext_vector_type(4))) float float4v;
typedef __attribute__((ext_vector_type(4))) unsigned short ushort4v;
typedef __attribute__((ext_vector_type(8))) unsigned short ushort8v;

__device__ __forceinline__ unsigned short f2b(float f) {
    uint32_t u = __builtin_bit_cast(uint32_t, f);
    u = (u + 0x7FFFu + ((u >> 16) & 1u)) >> 16;
    return (unsigned short)u;
}

__device__ __forceinline__ void gload_lds16(const void* g, void* l) {
    __builtin_amdgcn_global_load_lds((const __attribute__((address_space(1))) void*)g,
                                     (__attribute__((address_space(3))) void*)l, 16, 0, 0);
}

// ---------------- transpose + (optional f32->bf16) convert ----------------
template <typename T>
__global__ __launch_bounds__(256) void transpose_cvt(const T* __restrict__ src,
                                                     unsigned short* __restrict__ dst,
                                                     int ldS, int ldD, int R, int C) {
    __shared__ unsigned short tl[64 * 66];
    int r0 = blockIdx.y << 6, c0 = blockIdx.x << 6;
    int tid = threadIdx.x;
#pragma unroll
    for (int it = 0; it < 4; ++it) {
        int e = (tid + it * 256) * 4;
        int rr = e >> 6, cc = e & 63;
        const T* sp = src + (size_t)(r0 + rr) * ldS + c0 + cc;
        if constexpr (sizeof(T) == 4) {
            float4v v = *(const float4v*)sp;
#pragma unroll
            for (int j = 0; j < 4; ++j) tl[rr * 66 + cc + j] = f2b(v[j]);
        } else {
            ushort4v v = *(const ushort4v*)sp;
#pragma unroll
            for (int j = 0; j < 4; ++j) tl[rr * 66 + cc + j] = v[j];
        }
    }
    __syncthreads();
#pragma unroll
    for (int it = 0; it < 2; ++it) {
        int e = tid + it * 256;
        int oc = e >> 3;
        int k8 = (e & 7) * 8;
        ushort8v w;
#pragma unroll
        for (int j = 0; j < 8; ++j) w[j] = tl[(k8 + j) * 66 + oc];
        *(ushort8v*)(dst + (size_t)(c0 + oc) * ldD + r0 + k8) = w;
    }
}

// ---------------- LayerNorm ----------------
__global__ __launch_bounds__(256) void ln_kernel(const float* __restrict__ x,
                                                 const float* __restrict__ sc,
                                                 const float* __restrict__ of,
                                                 unsigned short* __restrict__ h) {
    int row = blockIdx.x;
    int tid = threadIdx.x, lane = tid & 63, wave = tid >> 6;
    const float4v* xr = (const float4v*)(x + (size_t)row * DM);
    float4v v[4];
    float s = 0.f, s2 = 0.f;
#pragma unroll
    for (int i = 0; i < 4; ++i) {
        v[i] = xr[tid + i * 256];
#pragma unroll
        for (int j = 0; j < 4; ++j) { s += v[i][j]; s2 += v[i][j] * v[i][j]; }
    }
#pragma unroll
    for (int o = 1; o < 64; o <<= 1) { s += __shfl_xor(s, o); s2 += __shfl_xor(s2, o); }
    __shared__ float rs[4], rs2[4];
    if (lane == 0) { rs[wave] = s; rs2[wave] = s2; }
    __syncthreads();
    s = rs[0] + rs[1] + rs[2] + rs[3];
    s2 = rs2[0] + rs2[1] + rs2[2] + rs2[3];
    float mean = s * (1.0f / DM);
    float var = s2 * (1.0f / DM) - mean * mean;
    float inv = rsqrtf(var + 1e-5f);
#pragma unroll
    for (int i = 0; i < 4; ++i) {
        int c = (tid + i * 256) * 4;
        ushort4v o4;
#pragma unroll
        for (int j = 0; j < 4; ++j)
            o4[j] = f2b((v[i][j] - mean) * inv * sc[c + j] + of[c + j]);
        *(ushort4v*)(h + (size_t)row * DM + c) = o4;
    }
}

// ---------------- 4-phase pipelined GEMM: C[M,N] = A[M,K] * BT[N,K]^T ----------------
// BM=256, BN=128, BK=64, 512 threads (8 waves 4Mx2N), per-wave 64x64 output.
// A: 2-deep dbuf (64KB), B: 3-ring (48KB), XOR swizzle (row&7)<<4 (conflict-free, verified r2).
// Iteration = 2 K-tiles = 4 phases; each phase = {ds_read frags, stage half, BAR, lgkm(0),
// setprio(1), 16 MFMA, setprio(0), BAR}. vmcnt(6) once per K-tile (never 0 in steady state).
#define MF(a, b, c) __builtin_amdgcn_mfma_f32_16x16x32_bf16(a, b, c, 0, 0, 0)
#define SB() __builtin_amdgcn_sched_barrier(0)
#define BAR()                          \
    SB();                              \
    __builtin_amdgcn_s_barrier();      \
    SB()
#define LGKM0()                                            \
    asm volatile("s_waitcnt lgkmcnt(0)" ::: "memory");     \
    SB()
#define VMC6()                                             \
    asm volatile("s_waitcnt vmcnt(6)" ::: "memory");       \
    SB()
#define VMC0()                                             \
    asm volatile("s_waitcnt vmcnt(0)" ::: "memory");       \
    SB()

#define LDAQ(BUF)                                                              \
    _Pragma("unroll") for (int fi = 0; fi < 4; ++fi) {                         \
        aQ[fi][0] = *(const short8*)((BUF) + (arow + fi * 16) * 64 + ca0);     \
        aQ[fi][1] = *(const short8*)((BUF) + (arow + fi * 16) * 64 + ca1);     \
    }
#define LDBQ(DST, BUF, J)                                                      \
    _Pragma("unroll") for (int fj = 0; fj < 2; ++fj) {                         \
        DST[fj][0] = *(const short8*)((BUF) + (brow + ((J) + fj) * 16) * 64 + cb0); \
        DST[fj][1] = *(const short8*)((BUF) + (brow + ((J) + fj) * 16) * 64 + cb1); \
    }
#define MFMA16(BQ, J)                                                          \
    __builtin_amdgcn_s_setprio(1);                                             \
    _Pragma("unroll") for (int fi = 0; fi < 4; ++fi)                           \
        _Pragma("unroll") for (int fj = 0; fj < 2; ++fj)                       \
            acc[fi][(J) + fj] = MF(aQ[fi][0], BQ[fj][0], acc[fi][(J) + fj]);   \
    _Pragma("unroll") for (int fi = 0; fi < 4; ++fi)                           \
        _Pragma("unroll") for (int fj = 0; fj < 2; ++fj)                       \
            acc[fi][(J) + fj] = MF(aQ[fi][1], BQ[fj][1], acc[fi][(J) + fj]);   \
    __builtin_amdgcn_s_setprio(0);

#define ITER(LAST)                                    \
    {                                                 \
        const unsigned short* a0 = aL[u & 1];         \
        const unsigned short* b0 = bL[u % 3];         \
        const unsigned short* a1 = aL[(u + 1) & 1];   \
        const unsigned short* b1 = bL[(u + 1) % 3];   \
        /* ph1: tile u, all A frags + B lo */         \
        LDAQ(a0);                                     \
        LDBQ(bQ0, b0, 0);                             \
        if (!(LAST)) stageB(u + 2);                   \
        BAR();                                        \
        LGKM0();                                      \
        MFMA16(bQ0, 0);                               \
        BAR();                                        \
        /* ph2: B hi */                               \
        LDBQ(bQ1, b0, 2);                             \
        if (!(LAST)) stageA(u + 2);                   \
        BAR();                                        \
        LGKM0();                                      \
        MFMA16(bQ1, 2);                               \
        if (LAST) { VMC0(); } else { VMC6(); }        \
        BAR();                                        \
        /* ph3: tile u+1 */                           \
        LDAQ(a1);                                     \
        LDBQ(bQ0, b1, 0);                             \
        if (!(LAST)) stageB(u + 3);                   \
        BAR();                                        \
        LGKM0();                                      \
        MFMA16(bQ0, 0);                               \
        BAR();                                        \
        /* ph4 */                                     \
        LDBQ(bQ1, b1, 2);                             \
        if (!(LAST)) stageA(u + 3);                   \
        BAR();                                        \
        LGKM0();                                      \
        MFMA16(bQ1, 2);                               \
        if (!(LAST)) { VMC6(); }                      \
        BAR();                                        \
    }

template <int EPI>
__global__ __launch_bounds__(512, 2) void gemm4ph(const unsigned short* __restrict__ A,
                                                  const unsigned short* __restrict__ BT,
                                                  void* __restrict__ Cout,
                                                  int M, int N, int K, int ldc,
                                                  const float* __restrict__ bias,
                                                  const float* __restrict__ addm) {
    __shared__ unsigned short aL[2][256 * 64];  // 64 KB
    __shared__ unsigned short bL[3][128 * 64];  // 48 KB

    const int nbx = N >> 7;
    const int nwg = (M >> 8) * nbx;
    int wg = blockIdx.x;
    wg = (wg & 7) * (nwg >> 3) + (wg >> 3);  // XCD swizzle (all grids %8==0)
    const int by = wg / nbx, bx = wg % nbx;
    const int bm0 = by << 8, bn0 = bx << 7;

    const int tid = threadIdx.x, lane = tid & 63, wave = tid >> 6;
    const int wm = wave >> 1, wn = wave & 1;
    const int l15 = lane & 15, kl = lane >> 4;

    // staging: thread covers 16B granule; row = tid>>3, phys col byte (tid&7)*16,
    // pre-swizzled source so linear LDS dest + swizzled reads agree (rule 21)
    const int rh = tid >> 3;
    const int cb_s = (tid & 7) << 4;
    const int kx = (cb_s ^ ((rh & 7) << 4)) >> 1;

    const unsigned short* Abase = A + ((size_t)bm0 + rh) * K + kx;
    const unsigned short* Bbase = BT + ((size_t)bn0 + rh) * K + kx;

    auto stageA = [&](int v) {
        const unsigned short* g = Abase + (size_t)v * 64;
        char* l = (char*)aL[v & 1] + (size_t)tid * 16;
        gload_lds16(g, l);
        gload_lds16(g + (size_t)64 * K, l + 8192);
        gload_lds16(g + (size_t)128 * K, l + 16384);
        gload_lds16(g + (size_t)192 * K, l + 24576);
    };
    auto stageB = [&](int v) {
        const unsigned short* g = Bbase + (size_t)v * 64;
        char* l = (char*)bL[v % 3] + (size_t)tid * 16;
        gload_lds16(g, l);
        gload_lds16(g + (size_t)64 * K, l + 8192);
    };

    // fragment read addressing (swizzled)
    const int arow = wm * 64 + l15;
    const int brow = wn * 64 + l15;
    const int sa = (arow & 7) << 4;
    const int sb = (brow & 7) << 4;
    const int ca0 = ((kl * 16) ^ sa) >> 1;
    const int ca1 = ((64 + kl * 16) ^ sa) >> 1;
    const int cb0 = ((kl * 16) ^ sb) >> 1;
    const int cb1 = ((64 + kl * 16) ^ sb) >> 1;

    f32x4 acc[4][4];
#pragma unroll
    for (int i = 0; i < 4; ++i)
#pragma unroll
        for (int j = 0; j < 4; ++j) acc[i][j] = (f32x4){0.f, 0.f, 0.f, 0.f};

    short8 aQ[4][2], bQ0[2][2], bQ1[2][2];

    // prologue: tiles 0 and 1 (12 loads); wait tile 0 (keep 6 in flight)
    stageB(0); stageA(0); stageB(1); stageA(1);
    VMC6();
    BAR();

    const int NI = K >> 7;  // 2 K-tiles per iteration
    int u = 0;
    for (int it = 0; it < NI - 1; ++it, u += 2) ITER(false);
    ITER(true);

    // epilogue
    const int r0 = bm0 + wm * 64 + kl * 4;
    const int c0g = bn0 + wn * 64 + l15;
#pragma unroll
    for (int i = 0; i < 4; ++i) {
#pragma unroll
        for (int j = 0; j < 4; ++j) {
            int col = c0g + j * 16;
#pragma unroll
            for (int r = 0; r < 4; ++r) {
                int row = r0 + i * 16 + r;
                float v = acc[i][j][r];
                if constexpr (EPI == 0) {
                    ((unsigned short*)Cout)[(size_t)row * ldc + col] = f2b(v);
                } else if constexpr (EPI == 1) {
                    ((float*)Cout)[(size_t)row * ldc + col] = v;
                } else if constexpr (EPI == 2) {
                    v += bias[col];
                    float t = tanhf(0.7978845608f * (v + 0.044715f * v * v * v));
                    ((unsigned short*)Cout)[(size_t)row * ldc + col] = f2b(0.5f * v * (1.0f + t));
                } else {
                    v += bias[col] + addm[(size_t)row * ldc + col];
                    ((float*)Cout)[(size_t)row * ldc + col] = v;
                }
            }
        }
    }
}

// ---------------- flash attention ----------------
__global__ __launch_bounds__(256, 2) void attn_kernel(const unsigned short* __restrict__ qkv,
                                                      const unsigned short* __restrict__ vT,
                                                      const float* __restrict__ bias,
                                                      unsigned short* __restrict__ attn_vec) {
    __shared__ unsigned short kL[64 * 264];
    __shared__ unsigned short vL[256 * 72];
    __shared__ unsigned short pL[4][16 * 72];

    int qb = blockIdx.x, head = blockIdx.y;
    int tid = threadIdx.x, lane = tid & 63, wave = tid >> 6;
    int q16 = lane & 15, q4 = lane >> 4;

    short8 qf[8];
    {
        const unsigned short* qp =
            qkv + (size_t)(qb * 64 + wave * 16 + q16) * (3 * DM) + head * DHEAD + (q4 << 3);
#pragma unroll
        for (int kk = 0; kk < 8; ++kk) qf[kk] = *(const short8*)(qp + kk * 32);
    }

    f32x4 o[16];
#pragma unroll
    for (int d = 0; d < 16; ++d) o[d] = (f32x4){0.f, 0.f, 0.f, 0.f};
    float m_run[4] = {-INFINITY, -INFINITY, -INFINITY, -INFINITY};
    float l_run[4] = {0.f, 0.f, 0.f, 0.f};
    int qrow0 = qb * 64 + wave * 16 + q4 * 4;

    for (int t = 0; t <= qb; ++t) {
        int kv0 = t * 64;
#pragma unroll
        for (int rr = 0; rr < 8; ++rr) {
            int i = tid + rr * 256;
            int row = i >> 5, c8 = (i & 31) << 3;
            *(ushort8v*)(kL + row * 264 + c8) =
                *(const ushort8v*)(qkv + (size_t)(kv0 + row) * (3 * DM) + DM + head * DHEAD + c8);
        }
#pragma unroll
        for (int rr = 0; rr < 8; ++rr) {
            int i = tid + rr * 256;
            int d = i >> 3, c8 = (i & 7) << 3;
            *(ushort8v*)(vL + d * 72 + c8) =
                *(const ushort8v*)(vT + (size_t)(head * DHEAD + d) * SEQ + kv0 + c8);
        }
        __syncthreads();

        f32x4 s[4];
#pragma unroll
        for (int c = 0; c < 4; ++c) s[c] = (f32x4){0.f, 0.f, 0.f, 0.f};
#pragma unroll
        for (int kk = 0; kk < 8; ++kk) {
#pragma unroll
            for (int c = 0; c < 4; ++c) {
                short8 kf = *(const short8*)(kL + (c * 16 + q16) * 264 + kk * 32 + (q4 << 3));
                s[c] = __builtin_amdgcn_mfma_f32_16x16x32_bf16(qf[kk], kf, s[c], 0, 0, 0);
            }
        }

        bool diag = (t == qb);
#pragma unroll
        for (int r = 0; r < 4; ++r) {
            int qr = qrow0 + r;
            float sv[4];
#pragma unroll
            for (int c = 0; c < 4; ++c) {
                float vv = s[c][r] * 0.0625f + bias[(size_t)qr * SEQ + kv0 + c * 16 + q16];
                if (diag && (kv0 + c * 16 + q16) > qr) vv = -1e30f;
                sv[c] = vv;
            }
            float m = fmaxf(fmaxf(sv[0], sv[1]), fmaxf(sv[2], sv[3]));
#pragma unroll
            for (int off = 1; off < 16; off <<= 1) m = fmaxf(m, __shfl_xor(m, off));
            float mn = fmaxf(m_run[r], m);
            float alpha = __expf(m_run[r] - mn);
            float psum = 0.f;
#pragma unroll
            for (int c = 0; c < 4; ++c) {
                float p = __expf(sv[c] - mn);
                psum += p;
                pL[wave][(q4 * 4 + r) * 72 + c * 16 + q16] = f2b(p);
            }
#pragma unroll
            for (int off = 1; off < 16; off <<= 1) psum += __shfl_xor(psum, off);
            l_run[r] = l_run[r] * alpha + psum;
            m_run[r] = mn;
#pragma unroll
            for (int d = 0; d < 16; ++d) o[d][r] *= alpha;
        }

#pragma unroll
        for (int ks = 0; ks < 2; ++ks) {
            short8 pa = *(const short8*)(pL[wave] + q16 * 72 + ks * 32 + (q4 << 3));
#pragma unroll
            for (int d = 0; d < 16; ++d) {
                short8 vb = *(const short8*)(vL + (d * 16 + q16) * 72 + ks * 32 + (q4 << 3));
                o[d] = __builtin_amdgcn_mfma_f32_16x16x32_bf16(pa, vb, o[d], 0, 0, 0);
            }
        }
        __syncthreads();
    }

#pragma unroll
    for (int r = 0; r < 4; ++r) {
        float inv = 1.0f / l_run[r];
#pragma unroll
        for (int d = 0; d < 16; ++d)
            attn_vec[(size_t)(qrow0 + r) * DM + head * DHEAD + d * 16 + q16] = f2b(o[d][r] * inv);
    }
}

// ---------------- launch ----------------
extern "C" void kernel_launch(void* const* d_in, const int* in_sizes, int n_in,
                              void* d_out, int out_size, void* d_ws, size_t ws_size,
                              hipStream_t stream) {
    const float* x = (const float*)d_in[0];
    const float* attn_bias = (const float*)d_in[1];
    const float* ln_scale = (const float*)d_in[2];
    const float* ln_offset = (const float*)d_in[3];
    const float* wq = (const float*)d_in[4];
    const float* wk = (const float*)d_in[5];
    const float* wv = (const float*)d_in[6];
    const float* wo = (const float*)d_in[7];
    const float* w_ffn = (const float*)d_in[8];
    const float* b_ffn = (const float*)d_in[9];
    const float* w_ffn_o = (const float*)d_in[10];
    const float* b_ffn_o = (const float*)d_in[11];
    float* out = (float*)d_out;

    char* p = (char*)d_ws;
    unsigned short* WT_qkv = (unsigned short*)p; p += (size_t)3 * DM * DM * 2;
    unsigned short* WT_o = (unsigned short*)p;   p += (size_t)DM * DM * 2;
    unsigned short* WT_f1 = (unsigned short*)p;  p += (size_t)DFF * DM * 2;
    unsigned short* WT_f2 = (unsigned short*)p;  p += (size_t)DM * DFF * 2;
    unsigned short* hB = (unsigned short*)p;     p += (size_t)SEQ * DM * 2;
    unsigned short* qkvB = (unsigned short*)p;   p += (size_t)SEQ * 3 * DM * 2;
    unsigned short* vTB = (unsigned short*)p;    p += (size_t)DM * SEQ * 2;
    unsigned short* avB = (unsigned short*)p;    p += (size_t)SEQ * DM * 2;
    float* attn_out = (float*)p;                 p += (size_t)SEQ * DM * 4;
    unsigned short* ffB = (unsigned short*)p;    p += (size_t)SEQ * DFF * 2;

    transpose_cvt<float><<<dim3(DM / 64, DM / 64), 256, 0, stream>>>(wq, WT_qkv, DM, DM, DM, DM);
    transpose_cvt<float><<<dim3(DM / 64, DM / 64), 256, 0, stream>>>(wk, WT_qkv + (size_t)DM * DM, DM, DM, DM, DM);
    transpose_cvt<float><<<dim3(DM / 64, DM / 64), 256, 0, stream>>>(wv, WT_qkv + (size_t)2 * DM * DM, DM, DM, DM, DM);
    transpose_cvt<float><<<dim3(DM / 64, DM / 64), 256, 0, stream>>>(wo, WT_o, DM, DM, DM, DM);
    transpose_cvt<float><<<dim3(DFF / 64, DM / 64), 256, 0, stream>>>(w_ffn, WT_f1, DFF, DM, DM, DFF);
    transpose_cvt<float><<<dim3(DM / 64, DFF / 64), 256, 0, stream>>>(w_ffn_o, WT_f2, DM, DFF, DFF, DM);

    ln_kernel<<<SEQ, 256, 0, stream>>>(x, ln_scale, ln_offset, hB);

    // QKV: 8*96 = 768 blocks (3/CU)
    gemm4ph<0><<<(SEQ / 256) * (3 * DM / 128), 512, 0, stream>>>(hB, WT_qkv, qkvB, SEQ, 3 * DM, DM, 3 * DM, nullptr, nullptr);
    transpose_cvt<unsigned short><<<dim3(DM / 64, SEQ / 64), 256, 0, stream>>>(qkvB + 2 * DM, vTB, 3 * DM, SEQ, SEQ, DM);

    attn_kernel<<<dim3(SEQ / 64, NHEADS), 256, 0, stream>>>(qkvB, vTB, attn_bias, avB);

    // WO: 256 blocks (1/CU)
    gemm4ph<1><<<(SEQ / 256) * (DM / 128), 512, 0, stream>>>(avB, WT_o, attn_out, SEQ, DM, DM, DM, nullptr, nullptr);
    // FFN1: 1024 blocks (4/CU)
    gemm4ph<2><<<(SEQ / 256) * (DFF / 128), 512, 0, stream>>>(hB, WT_f1, ffB, SEQ, DFF, DM, DFF, b_ffn, nullptr);
    // FFN2: 256 blocks (1/CU)
    gemm4ph<3><<<(SEQ / 256) * (DM / 128), 512, 0, stream>>>(ffB, WT_f2, out, SEQ, DM, DFF, DM, b_ffn_o, attn_out);
}

// Round 4
// 1463.329 us; speedup vs baseline: 1.2535x; 1.2535x over previous
//
#include <hip/hip_runtime.h>
#include <stdint.h>

#define SEQ 2048
#define DM 4096
#define NHEADS 16
#define DHEAD 256
#define DFF 16384

typedef __attribute__((ext_vector_type(8))) short short8;
typedef __attribute__((ext_vector_type(4))) float f32x4;
typedef __attribute__((ext_vector_type(4))) float float4v;
typedef __attribute__((ext_vector_type(4))) unsigned short ushort4v;
typedef __attribute__((ext_vector_type(8))) unsigned short ushort8v;

__device__ __forceinline__ unsigned short f2b(float f) {
    uint32_t u = __builtin_bit_cast(uint32_t, f);
    u = (u + 0x7FFFu + ((u >> 16) & 1u)) >> 16;
    return (unsigned short)u;
}

__device__ __forceinline__ void gload_lds16(const void* g, void* l) {
    __builtin_amdgcn_global_load_lds((const __attribute__((address_space(1))) void*)g,
                                     (__attribute__((address_space(3))) void*)l, 16, 0, 0);
}

// ---------------- transpose + (optional f32->bf16) convert ----------------
template <typename T>
__global__ __launch_bounds__(256) void transpose_cvt(const T* __restrict__ src,
                                                     unsigned short* __restrict__ dst,
                                                     int ldS, int ldD, int R, int C) {
    __shared__ unsigned short tl[64 * 66];
    int r0 = blockIdx.y << 6, c0 = blockIdx.x << 6;
    int tid = threadIdx.x;
#pragma unroll
    for (int it = 0; it < 4; ++it) {
        int e = (tid + it * 256) * 4;
        int rr = e >> 6, cc = e & 63;
        const T* sp = src + (size_t)(r0 + rr) * ldS + c0 + cc;
        if constexpr (sizeof(T) == 4) {
            float4v v = *(const float4v*)sp;
#pragma unroll
            for (int j = 0; j < 4; ++j) tl[rr * 66 + cc + j] = f2b(v[j]);
        } else {
            ushort4v v = *(const ushort4v*)sp;
#pragma unroll
            for (int j = 0; j < 4; ++j) tl[rr * 66 + cc + j] = v[j];
        }
    }
    __syncthreads();
#pragma unroll
    for (int it = 0; it < 2; ++it) {
        int e = tid + it * 256;
        int oc = e >> 3;
        int k8 = (e & 7) * 8;
        ushort8v w;
#pragma unroll
        for (int j = 0; j < 8; ++j) w[j] = tl[(k8 + j) * 66 + oc];
        *(ushort8v*)(dst + (size_t)(c0 + oc) * ldD + r0 + k8) = w;
    }
}

// ---------------- LayerNorm ----------------
__global__ __launch_bounds__(256) void ln_kernel(const float* __restrict__ x,
                                                 const float* __restrict__ sc,
                                                 const float* __restrict__ of,
                                                 unsigned short* __restrict__ h) {
    int row = blockIdx.x;
    int tid = threadIdx.x, lane = tid & 63, wave = tid >> 6;
    const float4v* xr = (const float4v*)(x + (size_t)row * DM);
    float4v v[4];
    float s = 0.f, s2 = 0.f;
#pragma unroll
    for (int i = 0; i < 4; ++i) {
        v[i] = xr[tid + i * 256];
#pragma unroll
        for (int j = 0; j < 4; ++j) { s += v[i][j]; s2 += v[i][j] * v[i][j]; }
    }
#pragma unroll
    for (int o = 1; o < 64; o <<= 1) { s += __shfl_xor(s, o); s2 += __shfl_xor(s2, o); }
    __shared__ float rs[4], rs2[4];
    if (lane == 0) { rs[wave] = s; rs2[wave] = s2; }
    __syncthreads();
    s = rs[0] + rs[1] + rs[2] + rs[3];
    s2 = rs2[0] + rs2[1] + rs2[2] + rs2[3];
    float mean = s * (1.0f / DM);
    float var = s2 * (1.0f / DM) - mean * mean;
    float inv = rsqrtf(var + 1e-5f);
#pragma unroll
    for (int i = 0; i < 4; ++i) {
        int c = (tid + i * 256) * 4;
        ushort4v o4;
#pragma unroll
        for (int j = 0; j < 4; ++j)
            o4[j] = f2b((v[i][j] - mean) * inv * sc[c + j] + of[c + j]);
        *(ushort4v*)(h + (size_t)row * DM + c) = o4;
    }
}

// ---------------- GEMM: C[M,N] = A[M,K](bf16) * BT[N,K]^T (bf16) ----------------
// 128x128 tile, BK=64, 4 waves (2Mx2N, 64x64 each), LDS 64KB -> 2 blocks/CU.
// Double-buffered, counted vmcnt(8) (never full-drain in steady state), raw barriers,
// compiler-scheduled reads/MFMAs (no sched_barrier pinning - r3 lesson).
// XOR swizzle (row&7)<<4: conflict-free (verified r2: SQ_LDS_BANK_CONFLICT=0).
#define MF(a, b, c) __builtin_amdgcn_mfma_f32_16x16x32_bf16(a, b, c, 0, 0, 0)

template <int EPI>
__global__ __launch_bounds__(256, 2) void gemm128(const unsigned short* __restrict__ A,
                                                  const unsigned short* __restrict__ BT,
                                                  void* __restrict__ Cout,
                                                  int M, int N, int K, int ldc,
                                                  const float* __restrict__ bias,
                                                  const float* __restrict__ addm) {
    __shared__ unsigned short aL[2][128 * 64];  // 32 KB
    __shared__ unsigned short bL[2][128 * 64];  // 32 KB

    const int nbx = N >> 7;
    const int nwg = (M >> 7) * nbx;
    int wg = blockIdx.x;
    wg = (wg & 7) * (nwg >> 3) + (wg >> 3);  // XCD swizzle (all grids %8==0)
    const int by = wg / nbx, bx = wg % nbx;
    const int bm0 = by << 7, bn0 = bx << 7;

    const int tid = threadIdx.x, lane = tid & 63, wave = tid >> 6;
    const int wm = wave >> 1, wn = wave & 1;
    const int l15 = lane & 15, kl = lane >> 4;

    // staging: thread -> 16B granule; row rh = tid>>3 (0..31, +32 per round),
    // pre-swizzled global source so linear LDS dest + swizzled reads agree.
    const int rh = tid >> 3;
    const int cb_s = (tid & 7) << 4;
    const int kx = (cb_s ^ ((rh & 7) << 4)) >> 1;

    const unsigned short* Abase = A + (size_t)(bm0 + rh) * K + kx;
    const unsigned short* Bbase = BT + (size_t)(bn0 + rh) * K + kx;

    auto stage = [&](int v) {
        const unsigned short* ga = Abase + (size_t)v * 64;
        const unsigned short* gb = Bbase + (size_t)v * 64;
        char* la = (char*)aL[v & 1] + tid * 16;
        char* lb = (char*)bL[v & 1] + tid * 16;
#pragma unroll
        for (int h = 0; h < 4; ++h) gload_lds16(ga + (size_t)(h * 32) * K, la + h * 4096);
#pragma unroll
        for (int h = 0; h < 4; ++h) gload_lds16(gb + (size_t)(h * 32) * K, lb + h * 4096);
    };

    // fragment read addressing (swizzled); (row+16i)&7 == row&7 so constants hold for all i
    const int arow = wm * 64 + l15;
    const int brow = wn * 64 + l15;
    const int sa = (arow & 7) << 4;
    const int sb = (brow & 7) << 4;
    const int ca0 = ((kl * 16) ^ sa) >> 1;
    const int ca1 = ((64 + kl * 16) ^ sa) >> 1;
    const int cb0 = ((kl * 16) ^ sb) >> 1;
    const int cb1 = ((64 + kl * 16) ^ sb) >> 1;

    f32x4 acc[4][4];
#pragma unroll
    for (int i = 0; i < 4; ++i)
#pragma unroll
        for (int j = 0; j < 4; ++j) acc[i][j] = (f32x4){0.f, 0.f, 0.f, 0.f};

    const int NT = K >> 6;
    stage(0);
    for (int u = 0; u < NT; ++u) {
        if (u + 1 < NT) {
            stage(u + 1);
            asm volatile("s_waitcnt vmcnt(8)" ::: "memory");  // tile u landed; u+1 in flight
        } else {
            asm volatile("s_waitcnt vmcnt(0)" ::: "memory");
        }
        __builtin_amdgcn_s_barrier();

        const unsigned short* aB = aL[u & 1];
        const unsigned short* bB = bL[u & 1];
        short8 af[4][2], bf[4][2];
#pragma unroll
        for (int i = 0; i < 4; ++i) {
            af[i][0] = *(const short8*)(aB + (arow + i * 16) * 64 + ca0);
            af[i][1] = *(const short8*)(aB + (arow + i * 16) * 64 + ca1);
        }
#pragma unroll
        for (int j = 0; j < 4; ++j) {
            bf[j][0] = *(const short8*)(bB + (brow + j * 16) * 64 + cb0);
            bf[j][1] = *(const short8*)(bB + (brow + j * 16) * 64 + cb1);
        }
#pragma unroll
        for (int kk = 0; kk < 2; ++kk)
#pragma unroll
            for (int i = 0; i < 4; ++i)
#pragma unroll
                for (int j = 0; j < 4; ++j)
                    acc[i][j] = MF(af[i][kk], bf[j][kk], acc[i][j]);

        // all my ds_reads done before any wave stages tile u+2 into buf[u&1]
        asm volatile("s_waitcnt lgkmcnt(0)" ::: "memory");
        __builtin_amdgcn_s_barrier();
    }

    // epilogue
    const int r0 = bm0 + wm * 64 + kl * 4;
    const int c0g = bn0 + wn * 64 + l15;
#pragma unroll
    for (int i = 0; i < 4; ++i) {
#pragma unroll
        for (int j = 0; j < 4; ++j) {
            int col = c0g + j * 16;
#pragma unroll
            for (int r = 0; r < 4; ++r) {
                int row = r0 + i * 16 + r;
                float v = acc[i][j][r];
                if constexpr (EPI == 0) {
                    ((unsigned short*)Cout)[(size_t)row * ldc + col] = f2b(v);
                } else if constexpr (EPI == 1) {
                    ((float*)Cout)[(size_t)row * ldc + col] = v;
                } else if constexpr (EPI == 2) {
                    v += bias[col];
                    float t = tanhf(0.7978845608f * (v + 0.044715f * v * v * v));
                    ((unsigned short*)Cout)[(size_t)row * ldc + col] = f2b(0.5f * v * (1.0f + t));
                } else {
                    v += bias[col] + addm[(size_t)row * ldc + col];
                    ((float*)Cout)[(size_t)row * ldc + col] = v;
                }
            }
        }
    }
}

// ---------------- flash attention ----------------
__global__ __launch_bounds__(256, 2) void attn_kernel(const unsigned short* __restrict__ qkv,
                                                      const unsigned short* __restrict__ vT,
                                                      const float* __restrict__ bias,
                                                      unsigned short* __restrict__ attn_vec) {
    __shared__ unsigned short kL[64 * 264];
    __shared__ unsigned short vL[256 * 72];
    __shared__ unsigned short pL[4][16 * 72];

    int qb = blockIdx.x, head = blockIdx.y;
    int tid = threadIdx.x, lane = tid & 63, wave = tid >> 6;
    int q16 = lane & 15, q4 = lane >> 4;

    short8 qf[8];
    {
        const unsigned short* qp =
            qkv + (size_t)(qb * 64 + wave * 16 + q16) * (3 * DM) + head * DHEAD + (q4 << 3);
#pragma unroll
        for (int kk = 0; kk < 8; ++kk) qf[kk] = *(const short8*)(qp + kk * 32);
    }

    f32x4 o[16];
#pragma unroll
    for (int d = 0; d < 16; ++d) o[d] = (f32x4){0.f, 0.f, 0.f, 0.f};
    float m_run[4] = {-INFINITY, -INFINITY, -INFINITY, -INFINITY};
    float l_run[4] = {0.f, 0.f, 0.f, 0.f};
    int qrow0 = qb * 64 + wave * 16 + q4 * 4;

    for (int t = 0; t <= qb; ++t) {
        int kv0 = t * 64;
#pragma unroll
        for (int rr = 0; rr < 8; ++rr) {
            int i = tid + rr * 256;
            int row = i >> 5, c8 = (i & 31) << 3;
            *(ushort8v*)(kL + row * 264 + c8) =
                *(const ushort8v*)(qkv + (size_t)(kv0 + row) * (3 * DM) + DM + head * DHEAD + c8);
        }
#pragma unroll
        for (int rr = 0; rr < 8; ++rr) {
            int i = tid + rr * 256;
            int d = i >> 3, c8 = (i & 7) << 3;
            *(ushort8v*)(vL + d * 72 + c8) =
                *(const ushort8v*)(vT + (size_t)(head * DHEAD + d) * SEQ + kv0 + c8);
        }
        __syncthreads();

        f32x4 s[4];
#pragma unroll
        for (int c = 0; c < 4; ++c) s[c] = (f32x4){0.f, 0.f, 0.f, 0.f};
#pragma unroll
        for (int kk = 0; kk < 8; ++kk) {
#pragma unroll
            for (int c = 0; c < 4; ++c) {
                short8 kf = *(const short8*)(kL + (c * 16 + q16) * 264 + kk * 32 + (q4 << 3));
                s[c] = __builtin_amdgcn_mfma_f32_16x16x32_bf16(qf[kk], kf, s[c], 0, 0, 0);
            }
        }

        bool diag = (t == qb);
#pragma unroll
        for (int r = 0; r < 4; ++r) {
            int qr = qrow0 + r;
            float sv[4];
#pragma unroll
            for (int c = 0; c < 4; ++c) {
                float vv = s[c][r] * 0.0625f + bias[(size_t)qr * SEQ + kv0 + c * 16 + q16];
                if (diag && (kv0 + c * 16 + q16) > qr) vv = -1e30f;
                sv[c] = vv;
            }
            float m = fmaxf(fmaxf(sv[0], sv[1]), fmaxf(sv[2], sv[3]));
#pragma unroll
            for (int off = 1; off < 16; off <<= 1) m = fmaxf(m, __shfl_xor(m, off));
            float mn = fmaxf(m_run[r], m);
            float alpha = __expf(m_run[r] - mn);
            float psum = 0.f;
#pragma unroll
            for (int c = 0; c < 4; ++c) {
                float p = __expf(sv[c] - mn);
                psum += p;
                pL[wave][(q4 * 4 + r) * 72 + c * 16 + q16] = f2b(p);
            }
#pragma unroll
            for (int off = 1; off < 16; off <<= 1) psum += __shfl_xor(psum, off);
            l_run[r] = l_run[r] * alpha + psum;
            m_run[r] = mn;
#pragma unroll
            for (int d = 0; d < 16; ++d) o[d][r] *= alpha;
        }

#pragma unroll
        for (int ks = 0; ks < 2; ++ks) {
            short8 pa = *(const short8*)(pL[wave] + q16 * 72 + ks * 32 + (q4 << 3));
#pragma unroll
            for (int d = 0; d < 16; ++d) {
                short8 vb = *(const short8*)(vL + (d * 16 + q16) * 72 + ks * 32 + (q4 << 3));
                o[d] = __builtin_amdgcn_mfma_f32_16x16x32_bf16(pa, vb, o[d], 0, 0, 0);
            }
        }
        __syncthreads();
    }

#pragma unroll
    for (int r = 0; r < 4; ++r) {
        float inv = 1.0f / l_run[r];
#pragma unroll
        for (int d = 0; d < 16; ++d)
            attn_vec[(size_t)(qrow0 + r) * DM + head * DHEAD + d * 16 + q16] = f2b(o[d][r] * inv);
    }
}

// ---------------- launch ----------------
extern "C" void kernel_launch(void* const* d_in, const int* in_sizes, int n_in,
                              void* d_out, int out_size, void* d_ws, size_t ws_size,
                              hipStream_t stream) {
    const float* x = (const float*)d_in[0];
    const float* attn_bias = (const float*)d_in[1];
    const float* ln_scale = (const float*)d_in[2];
    const float* ln_offset = (const float*)d_in[3];
    const float* wq = (const float*)d_in[4];
    const float* wk = (const float*)d_in[5];
    const float* wv = (const float*)d_in[6];
    const float* wo = (const float*)d_in[7];
    const float* w_ffn = (const float*)d_in[8];
    const float* b_ffn = (const float*)d_in[9];
    const float* w_ffn_o = (const float*)d_in[10];
    const float* b_ffn_o = (const float*)d_in[11];
    float* out = (float*)d_out;

    char* p = (char*)d_ws;
    unsigned short* WT_qkv = (unsigned short*)p; p += (size_t)3 * DM * DM * 2;
    unsigned short* WT_o = (unsigned short*)p;   p += (size_t)DM * DM * 2;
    unsigned short* WT_f1 = (unsigned short*)p;  p += (size_t)DFF * DM * 2;
    unsigned short* WT_f2 = (unsigned short*)p;  p += (size_t)DM * DFF * 2;
    unsigned short* hB = (unsigned short*)p;     p += (size_t)SEQ * DM * 2;
    unsigned short* qkvB = (unsigned short*)p;   p += (size_t)SEQ * 3 * DM * 2;
    unsigned short* vTB = (unsigned short*)p;    p += (size_t)DM * SEQ * 2;
    unsigned short* avB = (unsigned short*)p;    p += (size_t)SEQ * DM * 2;
    float* attn_out = (float*)p;                 p += (size_t)SEQ * DM * 4;
    unsigned short* ffB = (unsigned short*)p;    p += (size_t)SEQ * DFF * 2;

    transpose_cvt<float><<<dim3(DM / 64, DM / 64), 256, 0, stream>>>(wq, WT_qkv, DM, DM, DM, DM);
    transpose_cvt<float><<<dim3(DM / 64, DM / 64), 256, 0, stream>>>(wk, WT_qkv + (size_t)DM * DM, DM, DM, DM, DM);
    transpose_cvt<float><<<dim3(DM / 64, DM / 64), 256, 0, stream>>>(wv, WT_qkv + (size_t)2 * DM * DM, DM, DM, DM, DM);
    transpose_cvt<float><<<dim3(DM / 64, DM / 64), 256, 0, stream>>>(wo, WT_o, DM, DM, DM, DM);
    transpose_cvt<float><<<dim3(DFF / 64, DM / 64), 256, 0, stream>>>(w_ffn, WT_f1, DFF, DM, DM, DFF);
    transpose_cvt<float><<<dim3(DM / 64, DFF / 64), 256, 0, stream>>>(w_ffn_o, WT_f2, DM, DFF, DFF, DM);

    ln_kernel<<<SEQ, 256, 0, stream>>>(x, ln_scale, ln_offset, hB);

    // QKV: 16*96 = 1536 blocks (6/CU)
    gemm128<0><<<(SEQ / 128) * (3 * DM / 128), 256, 0, stream>>>(hB, WT_qkv, qkvB, SEQ, 3 * DM, DM, 3 * DM, nullptr, nullptr);
    transpose_cvt<unsigned short><<<dim3(DM / 64, SEQ / 64), 256, 0, stream>>>(qkvB + 2 * DM, vTB, 3 * DM, SEQ, SEQ, DM);

    attn_kernel<<<dim3(SEQ / 64, NHEADS), 256, 0, stream>>>(qkvB, vTB, attn_bias, avB);

    // WO: 16*32 = 512 blocks (2/CU)
    gemm128<1><<<(SEQ / 128) * (DM / 128), 256, 0, stream>>>(avB, WT_o, attn_out, SEQ, DM, DM, DM, nullptr, nullptr);
    // FFN1: 16*128 = 2048 blocks (8/CU)
    gemm128<2><<<(SEQ / 128) * (DFF / 128), 256, 0, stream>>>(hB, WT_f1, ffB, SEQ, DFF, DM, DFF, b_ffn, nullptr);
    // FFN2: 16*32 = 512 blocks (2/CU)
    gemm128<3><<<(SEQ / 128) * (DM / 128), 256, 0, stream>>>(ffB, WT_f2, out, SEQ, DM, DFF, DM, b_ffn_o, attn_out);
}